// Round 7
// baseline (629.984 us; speedup 1.0000x reference)
//
#include <hip/hip_runtime.h>
#include <math.h>

// ---------------------------------------------------------------------------
// LTFGW: N=4096, K=16 (k1=17), T=16, NT=16, D=128, OUTER=3, INNER=5.
//
// R12: combine the two empirical Pareto winners.
//   Ledger (6 experiments): fixed harness overhead F ~72-77us; best main ever
//   is R5's 71.5us = UNCONDITIONAL all-17-rows body (if-converted, 17
//   independent chains -> full ILP). Every "sparse" branchy variant (R7/R8/
//   R11) ran 80-92us despite ~7x less arithmetic: this kernel is VALU-issue/
//   ILP-bound, and branches serialize the surviving chains.
//   R11's in-reg Sinkhorn: REVERTED (bank conflicts 3.2M -> 14.8M, +VALU).
//   New: lean prep (R10, no adjbits) + R5-structure main with C1 floats in
//   an LDS table built in the prologue from direct adj gathers (R10-proven).
//   Uniform-address ds_reads broadcast (no conflicts); zero rows contribute
//   exactly 0.0 (bit-identical); cc1 = rowsum/17 (exact on {0,1}).
// R10 (kept): prep = {pgemm 32x64, xsq, scalars} only; gather lives in main.
// R5  (kept): unconditional grad/final loops, LDS Sinkhorn (Ush/Vsh).
// R2/R3 lesson (kept): scalar b32 C1 reads only, no bulk vector loads.
// ---------------------------------------------------------------------------

#define NN 4096
#define KNB 16
#define K1 17
#define TSTR 296      // Ksh per-template stride; 296%32==8 -> 2-way banks
#define TINYF 1e-16f

typedef const __attribute__((address_space(4))) float* c4fp;
typedef const __attribute__((address_space(4))) int*   c4ip;
__device__ __forceinline__ float sload(const float* p){ return *(c4fp)(unsigned long long)p; }
__device__ __forceinline__ int   sloadi(const int* p) { return *(c4ip)(unsigned long long)p; }

template<int CTRL>
__device__ __forceinline__ float dppmov(float x) {
  return __int_as_float(
      __builtin_amdgcn_update_dpp(0, __float_as_int(x), CTRL, 0xF, 0xF, true));
}
__device__ __forceinline__ float xor4v(float x) {        // xor4 = xor7 then xor3
  return dppmov<0x1B>(dppmov<0x141>(x));
}
__device__ __forceinline__ float rsum16(float x) {
  x += dppmov<0xB1>(x); x += dppmov<0x4E>(x);
  x += xor4v(x);        x += dppmov<0x128>(x);
  return x;
}
__device__ __forceinline__ float rmin16(float x) {
  x = fminf(x, dppmov<0xB1>(x)); x = fminf(x, dppmov<0x4E>(x));
  x = fminf(x, xor4v(x));        x = fminf(x, dppmov<0x128>(x));
  return x;
}
__device__ __forceinline__ float rmax16(float x) {
  x = fmaxf(x, dppmov<0xB1>(x)); x = fmaxf(x, dppmov<0x4E>(x));
  x = fmaxf(x, xor4v(x));        x = fmaxf(x, dppmov<0x128>(x));
  return x;
}
__device__ __forceinline__ float rcpn(float x) {   // rcp + 1 Newton step
  float r = __builtin_amdgcn_rcpf(x);
  return r * (2.f - x * r);
}

// cumulative XOR walk (verified R1/R4, absmax 0): after step r, g = src lane l^r
#define WSTEP(C, R) { g = dppmov<C>(g); acc = fmaf(g, c2reg[R], acc); }
#define WALK15() \
  WSTEP(0xB1,1)  WSTEP(0x1B,2)  WSTEP(0xB1,3)  WSTEP(0x141,4) \
  WSTEP(0xB1,5)  WSTEP(0x1B,6)  WSTEP(0xB1,7)  WSTEP(0x140,8) \
  WSTEP(0xB1,9)  WSTEP(0x1B,10) WSTEP(0xB1,11) WSTEP(0x141,12) \
  WSTEP(0xB1,13) WSTEP(0x1B,14) WSTEP(0xB1,15)

// ---------------------------------------------------------------------------
// prep_combined: one dispatch, block-range partitioned (R10-exact).
//   blocks [0,512)        : pgemm  P = x @ tf^T   (32x64 tile, 2 blocks/CU)
//   blocks [512,1536)     : xsq[n] = ||x[n]||^2   (trivial)
//   block  1536           : scalars (alpha,q,cq,tfsq)
// ---------------------------------------------------------------------------
#define PG_GEMM  512
#define PG_XSQ   (PG_GEMM + 1024)       // 1536
#define PG_SCAL  PG_XSQ                  // block 1536
#define PG_TOT   (PG_SCAL + 1)           // 1537

__global__ __launch_bounds__(256) void prep_combined(
    const float* __restrict__ x,
    const float* __restrict__ templates_,
    const float* __restrict__ tf, const float* __restrict__ q0,
    const float* __restrict__ alpha0,
    float* __restrict__ P,
    float* __restrict__ xsq,
    float* __restrict__ tfsq, float* __restrict__ qmat, float* __restrict__ cq,
    float* __restrict__ walpha) {
  __shared__ __align__(16) float smem[64*36 + 64*68];   // 26624 B arena
  const int b = blockIdx.x, tid = threadIdx.x;

  if (b < PG_GEMM) {
    // ---- pgemm: 32 rows x 64 cols per block, 2x4 per thread ----
    float (*As)[36] = (float (*)[36])smem;            // As[d][row], d<64
    float (*Bs)[68] = (float (*)[68])(smem + 64*36);  // Bs[d][col], d<64
    int tx = tid & 15, ty = tid >> 4;
    int r0 = (b >> 2) * 32, c0 = (b & 3) * 64;
    float acc[2][4] = {};
    for (int h = 0; h < 2; ++h) {
      __syncthreads();
#pragma unroll
      for (int q = 0; q < 2; ++q) {
        int f = tid + 256*q;
        int row = f >> 4, d4 = (f & 15) << 2;
        float4 a = *(const float4*)&x[(r0+row)*128 + h*64 + d4];
        As[d4+0][row]=a.x; As[d4+1][row]=a.y; As[d4+2][row]=a.z; As[d4+3][row]=a.w;
      }
#pragma unroll
      for (int q = 0; q < 4; ++q) {
        int f = tid + 256*q;
        int row = f >> 4, d4 = (f & 15) << 2;
        float4 bb = *(const float4*)&tf[(c0+row)*128 + h*64 + d4];
        Bs[d4+0][row]=bb.x; Bs[d4+1][row]=bb.y; Bs[d4+2][row]=bb.z; Bs[d4+3][row]=bb.w;
      }
      __syncthreads();
#pragma unroll
      for (int d = 0; d < 64; ++d) {
        float2 a = *(const float2*)&As[d][ty*2];
        float4 bb = *(const float4*)&Bs[d][tx*4];
        float av[2]={a.x,a.y}, bv[4]={bb.x,bb.y,bb.z,bb.w};
#pragma unroll
        for (int i = 0; i < 2; ++i)
#pragma unroll
          for (int j = 0; j < 4; ++j) acc[i][j] = fmaf(av[i], bv[j], acc[i][j]);
      }
    }
#pragma unroll
    for (int i = 0; i < 2; ++i) {
      float4 o; o.x=acc[i][0]; o.y=acc[i][1]; o.z=acc[i][2]; o.w=acc[i][3];
      *(float4*)&P[(r0 + ty*2 + i)*256 + c0 + tx*4] = o;
    }
    return;
  }

  if (b < PG_XSQ) {
    // ---- xsq: 4 rows per block, 1 wave per row ----
    int n = (b - PG_GEMM)*4 + (tid >> 6), lane = tid & 63;
    float2 v = *(const float2*)&x[n*128 + lane*2];
    float s = fmaf(v.x, v.x, v.y*v.y);
    s += __shfl_xor(s,1); s += __shfl_xor(s,2);  s += __shfl_xor(s,4);
    s += __shfl_xor(s,8); s += __shfl_xor(s,16); s += __shfl_xor(s,32);
    if (lane == 0) xsq[n] = s;
    return;
  }

  if (b == PG_SCAL) {
    // ---- scalars: alpha, q=softmax(q0), cq, tfsq ----
    int t = tid >> 4, l = tid & 15;
    if (tid == 0) walpha[0] = 1.f / (1.f + expf(-alpha0[0]));
    float qr[16]; float mx = -3.0e38f;
#pragma unroll
    for (int m = 0; m < 16; ++m) { qr[m] = q0[t*16+m]; mx = fmaxf(mx, qr[m]); }
    float s = 0.f;
#pragma unroll
    for (int m = 0; m < 16; ++m) { qr[m] = expf(qr[m]-mx); s += qr[m]; }
    float inv = 1.f / s;
    qmat[tid] = qr[l] * inv;
    float c = 0.f;
#pragma unroll
    for (int m = 0; m < 16; ++m) {
      float c2 = templates_[t*256 + l*16 + m];
      c = fmaf(qr[m]*inv, c2*c2, c);
    }
    cq[tid] = c;
    float ts = 0.f;
#pragma unroll
    for (int dq = 0; dq < 32; ++dq) {
      float4 v = *(const float4*)&tf[tid*128 + dq*4];
      ts = fmaf(v.x,v.x,ts); ts = fmaf(v.y,v.y,ts);
      ts = fmaf(v.z,v.z,ts); ts = fmaf(v.w,v.w,ts);
    }
    tfsq[tid] = ts;
    return;
  }
}

// ---------------------------------------------------------------------------
// main: 1 block/node, 256 thr = 16 templates x 16 cols.
// Prologue: 289 direct adj gathers -> LDS float table c1sh[17*17] (+row sums
// -> cc1). Body: R5-structure — unconditional all-17-rows masked-sum + walk,
// C1 values via uniform-address ds_read (broadcast, conflict-free).
// LDS: Ksh 18944 + Ush 1024 + Vsh 1024 + c1sh 1168 + cc1/nb 160 ~= 22.3 KB.
// ---------------------------------------------------------------------------
__global__ __launch_bounds__(256, 2) void ltfgw_main(
    const float* __restrict__ P, const float* __restrict__ adj,
    const float* __restrict__ xsq, const float* __restrict__ tfsq,
    const float* __restrict__ qmat, const float* __restrict__ cq,
    const float* __restrict__ walpha, const int* __restrict__ neighbors,
    const float* __restrict__ templates_, float* __restrict__ out) {
  __shared__ __align__(16) float Ksh[16 * TSTR];
  __shared__ __align__(16) float Ush[256];
  __shared__ __align__(16) float Vsh[256];
  __shared__ __align__(16) float c1sh[292];   // C1 as {0.0f,1.0f}, [i*17+j]
  __shared__ float cc1_sh[20];
  __shared__ int nb_sh[20];

  const int tid = threadIdx.x;
  const int t = tid >> 4, l = tid & 15;
  const int n = blockIdx.x;

  // ---- prologue: gather 17x17 C1 floats directly from adj ----
  if (tid < K1)
    nb_sh[tid] = (tid == 0) ? n : neighbors[n*KNB + tid - 1];
  __syncthreads();
  for (unsigned e = tid; e < 289; e += 256) {
    unsigned i = e / 17u, j = e % 17u;
    int ni = nb_sh[i], nj = nb_sh[j];
    float v = adj[ni*NN + nj];               // {0.0f, 1.0f} exactly
    c1sh[e] = (v != 0.f) ? 1.0f : 0.0f;
  }
  __syncthreads();
  if (tid < K1) {
    float s = 0.f;
#pragma unroll
    for (int j = 0; j < K1; ++j) s += c1sh[tid*17 + j];
    cc1_sh[tid] = s * (1.f/17.f);            // == popcount/17, exact
  }
  __syncthreads();

  int nbk[K1];
#pragma unroll
  for (int k = 0; k < K1; ++k)
    nbk[k] = __builtin_amdgcn_readfirstlane(nb_sh[k]);

  const float alpha = sload(walpha);
  const float oma = 1.f - alpha;
  const float na2 = -2.f * alpha;

  const float tfsq_l = tfsq[tid];
  const float cq_l   = cq[tid];
  const float q_l    = qmat[tid];

  // Mcol = (1-a)*M + a*cC
  float Mcol[K1];
#pragma unroll
  for (int k = 0; k < K1; ++k) {
    float xs  = sload(xsq + nbk[k]);
    float cc1 = cc1_sh[k];
    float pv  = P[nbk[k]*256 + tid];
    Mcol[k] = oma * (xs + tfsq_l - 2.f*pv) + alpha * (cc1 + cq_l);
  }

  // c2reg[r] = -2a * C2[t][l][l^r]  (pre-rotated for the XOR walk)
  float c2reg[16];
#pragma unroll
  for (int r = 0; r < 16; ++r)
    c2reg[r] = na2 * templates_[t*256 + l*16 + (l ^ r)];

  // G[j][l] in registers; init p*q
  float Gcol[K1];
#pragma unroll
  for (int j = 0; j < K1; ++j) Gcol[j] = (1.f/17.f) * q_l;

  const int tb = t * TSTR;
  float ur[16], u16 = 0.f, vm = 1.f;

#pragma unroll 1
  for (int outer = 0; outer < 3; ++outer) {
    // grad rows -> Kc[]: UNCONDITIONAL all 17 rows (R5 structure).
    // 17 independent chains -> full ILP; zero rows contribute exactly 0.0.
    float Kc[K1];
    float lo = 3.0e38f, hi = -3.0e38f;
#pragma unroll
    for (int i = 0; i < K1; ++i) {
      const float* c1r = &c1sh[i*17];
      float s = 0.f;
#pragma unroll
      for (int j = 0; j < K1; ++j) s = fmaf(c1r[j], Gcol[j], s);
      float g = s, acc = s * c2reg[0];
      WALK15()
      float gr = Mcol[i] + acc;
      Kc[i] = gr;
      lo = fminf(lo, gr); hi = fmaxf(hi, gr);
    }
    lo = rmin16(lo); hi = rmax16(hi);
    float eps = 0.1f * (hi - lo) + TINYF;
    float sc = 1.4426950408889634f * __builtin_amdgcn_rcpf(eps);
    float nsc = -sc, losc = lo * sc;
#pragma unroll
    for (int i = 0; i < K1; ++i) {
      Kc[i] = __builtin_amdgcn_exp2f(fmaf(Kc[i], nsc, losc));
      Ksh[tb + i*17 + l] = Kc[i];           // transpose write (same wave)
    }
    // row l of K for the u-update
    float Krow[16];
#pragma unroll
    for (int jq = 0; jq < 4; ++jq) {
      float4 v = *(const float4*)&Ksh[tb + l*17 + jq*4];
      Krow[jq*4+0]=v.x; Krow[jq*4+1]=v.y; Krow[jq*4+2]=v.z; Krow[jq*4+3]=v.w;
    }

    // Sinkhorn: 5 iters (u then v), v0 = 1 (R5/R7 LDS version)
    float vlane = 1.f;
    Vsh[tid] = 1.f;
#pragma unroll 1
    for (int it = 0; it < 5; ++it) {
      float vr[16];
#pragma unroll
      for (int q = 0; q < 4; ++q) {
        float4 v = *(const float4*)&Vsh[t*16 + q*4];
        vr[q*4+0]=v.x; vr[q*4+1]=v.y; vr[q*4+2]=v.z; vr[q*4+3]=v.w;
      }
      float w = 0.f;
#pragma unroll
      for (int j = 0; j < 16; ++j) w = fmaf(Krow[j], vr[j], w);
      float w16 = rsum16(Kc[16] * vlane);          // row 16 via DPP
      float um = (1.f/17.f) * rcpn(fmaxf(w,   TINYF));
      u16      = (1.f/17.f) * rcpn(fmaxf(w16, TINYF));
      Ush[tid] = um;
#pragma unroll
      for (int q = 0; q < 4; ++q) {
        float4 v = *(const float4*)&Ush[t*16 + q*4];
        ur[q*4+0]=v.x; ur[q*4+1]=v.y; ur[q*4+2]=v.z; ur[q*4+3]=v.w;
      }
      float sg = u16 * Kc[16];
#pragma unroll
      for (int k = 0; k < 16; ++k) sg = fmaf(ur[k], Kc[k], sg);
      vlane = q_l * rcpn(fmaxf(sg, TINYF));
      Vsh[tid] = vlane;
    }
    vm = vlane;
    // G = u * K * v
#pragma unroll
    for (int k = 0; k < 16; ++k) Gcol[k] = ur[k] * Kc[k] * vm;
    Gcol[16] = u16 * Kc[16] * vm;
  }

  // out[n,t] = sum_{i,l} (Mcol + delta) * G   (unconditional, R5 structure)
  float acc1 = 0.f;
#pragma unroll
  for (int i = 0; i < K1; ++i) acc1 = fmaf(Mcol[i], Gcol[i], acc1);
#pragma unroll
  for (int i = 0; i < K1; ++i) {
    const float* c1r = &c1sh[i*17];
    float s = 0.f;
#pragma unroll
    for (int j = 0; j < K1; ++j) s = fmaf(c1r[j], Gcol[j], s);
    float g = s, acc = s * c2reg[0];
    WALK15()
    acc1 = fmaf(acc, Gcol[i], acc1);
  }
  float accout = rsum16(acc1);
  if (l == 0) out[n*16 + t] = accout;
}

// ---------------------------------------------------------------------------
extern "C" void kernel_launch(void* const* d_in, const int* in_sizes, int n_in,
                              void* d_out, int out_size, void* d_ws, size_t ws_size,
                              hipStream_t stream) {
  const float* x          = (const float*)d_in[0];
  const float* adj        = (const float*)d_in[1];
  const int*   neighbors  = (const int*)  d_in[2];
  const float* templates_ = (const float*)d_in[3];
  const float* tfeat      = (const float*)d_in[4];
  const float* q0         = (const float*)d_in[5];
  const float* alpha0     = (const float*)d_in[6];
  float* out = (float*)d_out;

  float* ws     = (float*)d_ws;
  float* P      = ws;                       // 4096*256 floats
  float* xsq    = P + 4096*256;             // 4096
  float* tfsq   = xsq + 4096;               // 256
  float* qmat   = tfsq + 256;               // 256
  float* cq     = qmat + 256;               // 256
  float* walpha = cq + 256;                 // 1

  hipLaunchKernelGGL(prep_combined, dim3(PG_TOT), dim3(256), 0, stream,
                     x, templates_, tfeat, q0, alpha0,
                     P, xsq, tfsq, qmat, cq, walpha);
  hipLaunchKernelGGL(ltfgw_main, dim3(4096), dim3(256), 0, stream,
                     P, adj, xsq, tfsq, qmat, cq, walpha, neighbors,
                     templates_, out);
}

// Round 8
// 173.970 us; speedup vs baseline: 3.6212x; 3.6212x over previous
//
#include <hip/hip_runtime.h>
#include <math.h>

// ---------------------------------------------------------------------------
// LTFGW: N=4096, K=16 (k1=17), T=16, NT=16, D=128, OUTER=3, INNER=5.
//
// R13: R12 post-mortem — LDS C1 table in unrolled loops re-triggered the
//     R2/R3 scratch spill (VGPR 128, 1.7GB scratch, main 545us). R5's
//     unconditional body only worked because C1 came via SCALAR loads.
//     Reverted to R10 (best total, 175.0) and attacked its measured 38us
//     gather stall instead:
//       (1) C1 is SYMMETRIC (adj sym) -> gather upper triangle only:
//           153 loads (1/thread) instead of 289; set (i,j) AND (j,i) bits.
//           ~Halves scattered line traffic (92 -> ~60MB).
//       (2) Software-pipelined prologue: issue adj loads first (addresses
//           from direct per-thread neighbor reads, no LDS round trip), then
//           overlap nbk sloads + 17 P-row prefetches (the other latency
//           chain, previously serialized after the gather barrier) + c2reg/
//           q/cq/tfsq loads + Gcol init; atomicOr + ONE barrier at the end.
//     Body R10-exact; Mcol formula bit-identical (prefetched pv[]).
// R10 (kept): lean prep {pgemm 32x64, xsq, scalars}; gather lives in main.
// R7 (kept): body structure (uniform outer branch + volatile pin).
// R6 (kept): binary adj -> row bitmasks; cc1 = popcount/17.
// R2/R3 lesson (re-confirmed by R12): C1 via scalar/SGPR path only.
// ---------------------------------------------------------------------------

#define NN 4096
#define KNB 16
#define K1 17
#define TSTR 296      // Ksh per-template stride; 296%32==8 -> 2-way banks
#define TINYF 1e-16f

typedef const __attribute__((address_space(4))) float* c4fp;
typedef const __attribute__((address_space(4))) int*   c4ip;
__device__ __forceinline__ float sload(const float* p){ return *(c4fp)(unsigned long long)p; }
__device__ __forceinline__ int   sloadi(const int* p) { return *(c4ip)(unsigned long long)p; }

template<int CTRL>
__device__ __forceinline__ float dppmov(float x) {
  return __int_as_float(
      __builtin_amdgcn_update_dpp(0, __float_as_int(x), CTRL, 0xF, 0xF, true));
}
__device__ __forceinline__ float xor4v(float x) {        // xor4 = xor7 then xor3
  return dppmov<0x1B>(dppmov<0x141>(x));
}
__device__ __forceinline__ float rsum16(float x) {
  x += dppmov<0xB1>(x); x += dppmov<0x4E>(x);
  x += xor4v(x);        x += dppmov<0x128>(x);
  return x;
}
__device__ __forceinline__ float rmin16(float x) {
  x = fminf(x, dppmov<0xB1>(x)); x = fminf(x, dppmov<0x4E>(x));
  x = fminf(x, xor4v(x));        x = fminf(x, dppmov<0x128>(x));
  return x;
}
__device__ __forceinline__ float rmax16(float x) {
  x = fmaxf(x, dppmov<0xB1>(x)); x = fmaxf(x, dppmov<0x4E>(x));
  x = fmaxf(x, xor4v(x));        x = fmaxf(x, dppmov<0x128>(x));
  return x;
}
__device__ __forceinline__ float rcpn(float x) {   // rcp + 1 Newton step
  float r = __builtin_amdgcn_rcpf(x);
  return r * (2.f - x * r);
}

// cumulative XOR walk (verified R1/R4, absmax 0): after step r, g = src lane l^r
#define WSTEP(C, R) { g = dppmov<C>(g); acc = fmaf(g, c2reg[R], acc); }
#define WALK15() \
  WSTEP(0xB1,1)  WSTEP(0x1B,2)  WSTEP(0xB1,3)  WSTEP(0x141,4) \
  WSTEP(0xB1,5)  WSTEP(0x1B,6)  WSTEP(0xB1,7)  WSTEP(0x140,8) \
  WSTEP(0xB1,9)  WSTEP(0x1B,10) WSTEP(0xB1,11) WSTEP(0x141,12) \
  WSTEP(0xB1,13) WSTEP(0x1B,14) WSTEP(0xB1,15)

// ---------------------------------------------------------------------------
// prep_combined: one dispatch, block-range partitioned (R10-exact).
//   blocks [0,512)        : pgemm  P = x @ tf^T   (32x64 tile, 2 blocks/CU)
//   blocks [512,1536)     : xsq[n] = ||x[n]||^2   (trivial)
//   block  1536           : scalars (alpha,q,cq,tfsq)
// ---------------------------------------------------------------------------
#define PG_GEMM  512
#define PG_XSQ   (PG_GEMM + 1024)       // 1536
#define PG_SCAL  PG_XSQ                  // block 1536
#define PG_TOT   (PG_SCAL + 1)           // 1537

__global__ __launch_bounds__(256) void prep_combined(
    const float* __restrict__ x,
    const float* __restrict__ templates_,
    const float* __restrict__ tf, const float* __restrict__ q0,
    const float* __restrict__ alpha0,
    float* __restrict__ P,
    float* __restrict__ xsq,
    float* __restrict__ tfsq, float* __restrict__ qmat, float* __restrict__ cq,
    float* __restrict__ walpha) {
  __shared__ __align__(16) float smem[64*36 + 64*68];   // 26624 B arena
  const int b = blockIdx.x, tid = threadIdx.x;

  if (b < PG_GEMM) {
    // ---- pgemm: 32 rows x 64 cols per block, 2x4 per thread ----
    float (*As)[36] = (float (*)[36])smem;            // As[d][row], d<64
    float (*Bs)[68] = (float (*)[68])(smem + 64*36);  // Bs[d][col], d<64
    int tx = tid & 15, ty = tid >> 4;
    int r0 = (b >> 2) * 32, c0 = (b & 3) * 64;
    float acc[2][4] = {};
    for (int h = 0; h < 2; ++h) {
      __syncthreads();
#pragma unroll
      for (int q = 0; q < 2; ++q) {
        int f = tid + 256*q;
        int row = f >> 4, d4 = (f & 15) << 2;
        float4 a = *(const float4*)&x[(r0+row)*128 + h*64 + d4];
        As[d4+0][row]=a.x; As[d4+1][row]=a.y; As[d4+2][row]=a.z; As[d4+3][row]=a.w;
      }
#pragma unroll
      for (int q = 0; q < 4; ++q) {
        int f = tid + 256*q;
        int row = f >> 4, d4 = (f & 15) << 2;
        float4 bb = *(const float4*)&tf[(c0+row)*128 + h*64 + d4];
        Bs[d4+0][row]=bb.x; Bs[d4+1][row]=bb.y; Bs[d4+2][row]=bb.z; Bs[d4+3][row]=bb.w;
      }
      __syncthreads();
#pragma unroll
      for (int d = 0; d < 64; ++d) {
        float2 a = *(const float2*)&As[d][ty*2];
        float4 bb = *(const float4*)&Bs[d][tx*4];
        float av[2]={a.x,a.y}, bv[4]={bb.x,bb.y,bb.z,bb.w};
#pragma unroll
        for (int i = 0; i < 2; ++i)
#pragma unroll
          for (int j = 0; j < 4; ++j) acc[i][j] = fmaf(av[i], bv[j], acc[i][j]);
      }
    }
#pragma unroll
    for (int i = 0; i < 2; ++i) {
      float4 o; o.x=acc[i][0]; o.y=acc[i][1]; o.z=acc[i][2]; o.w=acc[i][3];
      *(float4*)&P[(r0 + ty*2 + i)*256 + c0 + tx*4] = o;
    }
    return;
  }

  if (b < PG_XSQ) {
    // ---- xsq: 4 rows per block, 1 wave per row ----
    int n = (b - PG_GEMM)*4 + (tid >> 6), lane = tid & 63;
    float2 v = *(const float2*)&x[n*128 + lane*2];
    float s = fmaf(v.x, v.x, v.y*v.y);
    s += __shfl_xor(s,1); s += __shfl_xor(s,2);  s += __shfl_xor(s,4);
    s += __shfl_xor(s,8); s += __shfl_xor(s,16); s += __shfl_xor(s,32);
    if (lane == 0) xsq[n] = s;
    return;
  }

  if (b == PG_SCAL) {
    // ---- scalars: alpha, q=softmax(q0), cq, tfsq ----
    int t = tid >> 4, l = tid & 15;
    if (tid == 0) walpha[0] = 1.f / (1.f + expf(-alpha0[0]));
    float qr[16]; float mx = -3.0e38f;
#pragma unroll
    for (int m = 0; m < 16; ++m) { qr[m] = q0[t*16+m]; mx = fmaxf(mx, qr[m]); }
    float s = 0.f;
#pragma unroll
    for (int m = 0; m < 16; ++m) { qr[m] = expf(qr[m]-mx); s += qr[m]; }
    float inv = 1.f / s;
    qmat[tid] = qr[l] * inv;
    float c = 0.f;
#pragma unroll
    for (int m = 0; m < 16; ++m) {
      float c2 = templates_[t*256 + l*16 + m];
      c = fmaf(qr[m]*inv, c2*c2, c);
    }
    cq[tid] = c;
    float ts = 0.f;
#pragma unroll
    for (int dq = 0; dq < 32; ++dq) {
      float4 v = *(const float4*)&tf[tid*128 + dq*4];
      ts = fmaf(v.x,v.x,ts); ts = fmaf(v.y,v.y,ts);
      ts = fmaf(v.z,v.z,ts); ts = fmaf(v.w,v.w,ts);
    }
    tfsq[tid] = ts;
    return;
  }
}

// ---------------------------------------------------------------------------
// main: 1 block/node, 256 thr = 16 templates x 16 cols (R10 body, exact).
// Prologue: software-pipelined symmetric gather — 153 upper-triangle adj
// loads (1/thread) issued first; nbk sloads + 17 P-row prefetches + c2reg/
// scalar loads + Gcol init overlap the latency; atomicOr + one barrier.
// ---------------------------------------------------------------------------
__global__ __launch_bounds__(256, 2) void ltfgw_main(
    const float* __restrict__ P, const float* __restrict__ adj,
    const float* __restrict__ xsq, const float* __restrict__ tfsq,
    const float* __restrict__ qmat, const float* __restrict__ cq,
    const float* __restrict__ walpha, const int* __restrict__ neighbors,
    const float* __restrict__ templates_, float* __restrict__ out) {
  __shared__ __align__(16) float Ksh[16 * TSTR];
  __shared__ __align__(16) float Ush[256];
  __shared__ __align__(16) float Vsh[256];
  __shared__ int rm_sh[20];

  const int tid = threadIdx.x;
  const int t = tid >> 4, l = tid & 15;
  const int n = blockIdx.x;

  // ---- zero masks; cheap barrier (nothing in flight yet) ----
  if (tid < 20) rm_sh[tid] = 0;
  __syncthreads();

  // ---- issue the C1 gather: upper triangle only (C1 symmetric) ----
  // e = i*17+j over {j>=i}: 150 elements have e<256 (own tid); the 3 with
  // e>=256 are remapped onto idle lower-triangle threads.
  int e = tid;
  if (tid == 17)      e = 15*17 + 15;
  else if (tid == 34) e = 15*17 + 16;
  else if (tid == 51) e = 16*17 + 16;
  const int gi = e / 17, gj = e % 17;
  const bool gact = (gj >= gi);
  float gv = 0.f;
  if (gact) {
    int ni = (gi == 0) ? n : neighbors[n*KNB + gi - 1];
    int nj = (gj == 0) ? n : neighbors[n*KNB + gj - 1];
    gv = adj[(long long)ni * NN + nj];      // {0.0f, 1.0f} exactly
  }

  // ---- overlap: everything that doesn't need the masks ----
  int nbk[K1];
  nbk[0] = n;
#pragma unroll
  for (int k = 1; k < K1; ++k) nbk[k] = sloadi(neighbors + n*KNB + (k-1));

  const float alpha = sload(walpha);
  const float oma = 1.f - alpha;
  const float na2 = -2.f * alpha;

  const float tfsq_l = tfsq[tid];
  const float cq_l   = cq[tid];
  const float q_l    = qmat[tid];

  // prefetch the 17 P values (the other big latency chain)
  float pv[K1];
#pragma unroll
  for (int k = 0; k < K1; ++k) pv[k] = P[nbk[k]*256 + tid];

  // c2reg[r] = -2a * C2[t][l][l^r]  (pre-rotated for the XOR walk)
  float c2reg[16];
#pragma unroll
  for (int r = 0; r < 16; ++r)
    c2reg[r] = na2 * templates_[t*256 + l*16 + (l ^ r)];

  // G[j][l] in registers; init p*q
  float Gcol[K1];
#pragma unroll
  for (int j = 0; j < K1; ++j) Gcol[j] = (1.f/17.f) * q_l;

  // ---- commit gather bits (both halves of the symmetric pair) ----
  if (gact && gv != 0.f) {
    atomicOr(&rm_sh[gi], 1 << gj);
    if (gi != gj) atomicOr(&rm_sh[gj], 1 << gi);
  }
  __syncthreads();

  int rm[K1];
#pragma unroll
  for (int k = 0; k < K1; ++k)
    rm[k] = __builtin_amdgcn_readfirstlane(rm_sh[k]);

  // Mcol = (1-a)*M + a*cC ; cc1 = popcount(row)/17 (C1 binary). Formula
  // bit-identical to R10; pv[] prefetched above.
  float Mcol[K1];
#pragma unroll
  for (int k = 0; k < K1; ++k) {
    float xs  = sload(xsq + nbk[k]);
    float cc1 = (float)__popc((unsigned)rm[k]) * (1.f/17.f);
    Mcol[k] = oma * (xs + tfsq_l - 2.f*pv[k]) + alpha * (cc1 + cq_l);
  }

  const int tb = t * TSTR;
  float ur[16], u16 = 0.f, vm = 1.f;

#pragma unroll 1
  for (int outer = 0; outer < 3; ++outer) {
    // grad rows -> Kc[]; only C1-nonzero rows do bit-sum + walk.
    // Volatile asm pins rmi inside the branch (R7-verified structure).
    float Kc[K1];
    float lo = 3.0e38f, hi = -3.0e38f;
#pragma unroll
    for (int i = 0; i < K1; ++i) {
      float gr = Mcol[i];
      int rmi = rm[i];
      if (rmi) {
        asm volatile("" : "+s"(rmi));
        float s = 0.f;
#pragma unroll
        for (int j = 0; j < K1; ++j)
          if (rmi & (1 << j)) s += Gcol[j];   // == fmaf({0,1},G,s) exactly
        float g = s, acc = s * c2reg[0];
        WALK15()
        gr += acc;
      }
      Kc[i] = gr;
      lo = fminf(lo, gr); hi = fmaxf(hi, gr);
    }
    lo = rmin16(lo); hi = rmax16(hi);
    float eps = 0.1f * (hi - lo) + TINYF;
    float sc = 1.4426950408889634f * __builtin_amdgcn_rcpf(eps);
    float nsc = -sc, losc = lo * sc;
#pragma unroll
    for (int i = 0; i < K1; ++i) {
      Kc[i] = __builtin_amdgcn_exp2f(fmaf(Kc[i], nsc, losc));
      Ksh[tb + i*17 + l] = Kc[i];           // transpose write (same wave)
    }
    // row l of K for the u-update
    float Krow[16];
#pragma unroll
    for (int jq = 0; jq < 4; ++jq) {
      float4 v = *(const float4*)&Ksh[tb + l*17 + jq*4];
      Krow[jq*4+0]=v.x; Krow[jq*4+1]=v.y; Krow[jq*4+2]=v.z; Krow[jq*4+3]=v.w;
    }

    // Sinkhorn: 5 iters (u then v), v0 = 1
    float vlane = 1.f;
    Vsh[tid] = 1.f;
#pragma unroll 1
    for (int it = 0; it < 5; ++it) {
      float vr[16];
#pragma unroll
      for (int q = 0; q < 4; ++q) {
        float4 v = *(const float4*)&Vsh[t*16 + q*4];
        vr[q*4+0]=v.x; vr[q*4+1]=v.y; vr[q*4+2]=v.z; vr[q*4+3]=v.w;
      }
      float w = 0.f;
#pragma unroll
      for (int j = 0; j < 16; ++j) w = fmaf(Krow[j], vr[j], w);
      float w16 = rsum16(Kc[16] * vlane);          // row 16 via DPP
      float um = (1.f/17.f) * rcpn(fmaxf(w,   TINYF));
      u16      = (1.f/17.f) * rcpn(fmaxf(w16, TINYF));
      Ush[tid] = um;
#pragma unroll
      for (int q = 0; q < 4; ++q) {
        float4 v = *(const float4*)&Ush[t*16 + q*4];
        ur[q*4+0]=v.x; ur[q*4+1]=v.y; ur[q*4+2]=v.z; ur[q*4+3]=v.w;
      }
      float sg = u16 * Kc[16];
#pragma unroll
      for (int k = 0; k < 16; ++k) sg = fmaf(ur[k], Kc[k], sg);
      vlane = q_l * rcpn(fmaxf(sg, TINYF));
      Vsh[tid] = vlane;
    }
    vm = vlane;
    // G = u * K * v
#pragma unroll
    for (int k = 0; k < 16; ++k) Gcol[k] = ur[k] * Kc[k] * vm;
    Gcol[16] = u16 * Kc[16] * vm;
  }

  // out[n,t] = sum_{i,l} (Mcol + delta) * G
  float acc1 = 0.f;
#pragma unroll
  for (int i = 0; i < K1; ++i) acc1 = fmaf(Mcol[i], Gcol[i], acc1);
#pragma unroll
  for (int i = 0; i < K1; ++i) {
    int rmi = rm[i];
    if (rmi) {
      asm volatile("" : "+s"(rmi));
      float s = 0.f;
#pragma unroll
      for (int j = 0; j < K1; ++j)
        if (rmi & (1 << j)) s += Gcol[j];
      float g = s, acc = s * c2reg[0];
      WALK15()
      acc1 = fmaf(acc, Gcol[i], acc1);
    }
  }
  float accout = rsum16(acc1);
  if (l == 0) out[n*16 + t] = accout;
}

// ---------------------------------------------------------------------------
extern "C" void kernel_launch(void* const* d_in, const int* in_sizes, int n_in,
                              void* d_out, int out_size, void* d_ws, size_t ws_size,
                              hipStream_t stream) {
  const float* x          = (const float*)d_in[0];
  const float* adj        = (const float*)d_in[1];
  const int*   neighbors  = (const int*)  d_in[2];
  const float* templates_ = (const float*)d_in[3];
  const float* tfeat      = (const float*)d_in[4];
  const float* q0         = (const float*)d_in[5];
  const float* alpha0     = (const float*)d_in[6];
  float* out = (float*)d_out;

  float* ws     = (float*)d_ws;
  float* P      = ws;                       // 4096*256 floats
  float* xsq    = P + 4096*256;             // 4096
  float* tfsq   = xsq + 4096;               // 256
  float* qmat   = tfsq + 256;               // 256
  float* cq     = qmat + 256;               // 256
  float* walpha = cq + 256;                 // 1

  hipLaunchKernelGGL(prep_combined, dim3(PG_TOT), dim3(256), 0, stream,
                     x, templates_, tfeat, q0, alpha0,
                     P, xsq, tfsq, qmat, cq, walpha);
  hipLaunchKernelGGL(ltfgw_main, dim3(4096), dim3(256), 0, stream,
                     P, adj, xsq, tfsq, qmat, cq, walpha, neighbors,
                     templates_, out);
}